// Round 1
// baseline (154.337 us; speedup 1.0000x reference)
//
#include <hip/hip_runtime.h>

// TT-linear, fp32 factored contraction (no dense 8192x8192 weight).
// x:     [128][8192]  flat in-index = i0*256 + i1*16 + i2
// core0: [1][32][32][4]   -> c0[o0*128 + i0*4 + r1]
// core1: [4][16][16][4]   -> c1[(r1*16+o1)*64 + i1*4 + r2]   (= [r1o1][i1r2])
// core2: [4][16][16][1]   -> c2[r2*256 + o2*16 + i2]
// out:   [128][8192]  flat out-index = o0*256 + o1*16 + o2
//
// y1[t][i0][o2][i1][r2] = sum_i2 x[t,i0,i1,i2] * c2[r2,o2,i2]         (ws)
// y2[t][k=i0*4+r1][c=o1*16+o2] = sum_{i1,r2} y1 * c1[r1,o1,i1,r2]     (ws)
// out[t][o0*256+c] = sum_k y2[t][k][c] * c0[o0*128+k] + bias

// ---------------- K1: x (x) c2 -> y1 --------------------------------------
// One thread produces 4 consecutive outputs (r2 = 0..3). 4096 blocks x 256.
__global__ void tt_k1(const float* __restrict__ x, const float* __restrict__ c2,
                      float* __restrict__ y1) {
    int q = blockIdx.x * 256 + threadIdx.x;          // quad id, 1048576 total
    int i1 = q & 15, o2 = (q >> 4) & 15, i0 = (q >> 8) & 31, t = q >> 13;
    const float4* x4 = reinterpret_cast<const float4*>(x + ((t << 13) | (i0 << 8) | (i1 << 4)));
    float xv[16];
#pragma unroll
    for (int m = 0; m < 4; ++m) {
        float4 v = x4[m];
        xv[4*m+0] = v.x; xv[4*m+1] = v.y; xv[4*m+2] = v.z; xv[4*m+3] = v.w;
    }
    float acc[4];
#pragma unroll
    for (int r2 = 0; r2 < 4; ++r2) {
        const float4* c4 = reinterpret_cast<const float4*>(c2 + r2*256 + o2*16);
        float s = 0.f;
#pragma unroll
        for (int m = 0; m < 4; ++m) {
            float4 v = c4[m];
            s += xv[4*m+0]*v.x + xv[4*m+1]*v.y + xv[4*m+2]*v.z + xv[4*m+3]*v.w;
        }
        acc[r2] = s;
    }
    reinterpret_cast<float4*>(y1)[q] = make_float4(acc[0], acc[1], acc[2], acc[3]);
}

// ---------------- K2: y1 (x) c1 -> y2  (+ c0 transpose) --------------------
// Block = (t, group of 8 i0), 512 blocks x 128 threads (2 waves).
// Lane <-> (i0loc, o2); all 64 r1o1 accumulators live in registers.
// c1 is read at wave-uniform indices -> scalar (SMEM) loads, SGPR-operand FMAs.
__global__ void tt_k2(const float* __restrict__ y1, const float* __restrict__ c1,
                      const float* __restrict__ c0, float* __restrict__ y2,
                      float* __restrict__ c0t) {
    __shared__ float y1s[128 * 68];                   // 8 i0 x 16 o2 rows, pad 64->68
    int b = blockIdx.x;
    int t = b >> 2, i0g = b & 3;
    int tid = threadIdx.x;                            // 128

    // fold-in: first 16 blocks transpose c0 -> c0t[k*32 + o0]
    if (b < 16) {
#pragma unroll
        for (int m = 0; m < 2; ++m) {
            int idx = b*256 + m*128 + tid;            // 4096 elems
            c0t[idx] = c0[(idx & 31)*128 + (idx >> 5)];
        }
    }

    // stage the 8x1024-float y1 tile into LDS (coalesced float4)
    const float4* y14 = reinterpret_cast<const float4*>(y1 + (t*32 + i0g*8)*1024);
#pragma unroll
    for (int k = 0; k < 16; ++k) {
        int fq = k*128 + tid;                         // 2048 quads
        float4 v = y14[fq];
        int row = fq >> 4, word = (fq & 15) << 2;
        *reinterpret_cast<float4*>(&y1s[row*68 + word]) = v;
    }
    __syncthreads();

    int lane = tid & 63, w = tid >> 6;
    int i0loc = (w << 2) | (lane >> 4);               // 0..7
    int o2 = lane & 15;

    float acc[64];
#pragma unroll
    for (int r = 0; r < 64; ++r) acc[r] = 0.f;

    const float4* c14 = reinterpret_cast<const float4*>(c1);
    const float* rowp = &y1s[(i0loc*16 + o2)*68];
#pragma unroll 2
    for (int j = 0; j < 16; ++j) {                    // i1r2 in chunks of 4
        float4 yv = *reinterpret_cast<const float4*>(rowp + (j << 2));
#pragma unroll
        for (int r = 0; r < 64; ++r) {                // r1o1 — wave-uniform c1 index
            float4 cv = c14[r*16 + j];
            acc[r] += yv.x*cv.x + yv.y*cv.y + yv.z*cv.z + yv.w*cv.w;
        }
    }

    int i0 = i0g*8 + i0loc;
    float* outp = y2 + (t*32 + i0)*1024 + o2;
#pragma unroll
    for (int r = 0; r < 64; ++r) outp[r*16] = acc[r];
}

// ---------------- K3: y2 (x) c0 + bias -> out ------------------------------
// Block = (t, half of o0), 256 blocks x 256 threads. Lane <-> column c.
// c0t read at wave-uniform indices -> scalar loads.
__global__ void tt_k3(const float* __restrict__ y2, const float* __restrict__ c0t,
                      const float* __restrict__ bias, float* __restrict__ out) {
    int b = blockIdx.x;
    int t = b >> 1, o0h = b & 1;
    int c = threadIdx.x;                              // 0..255
    float acc[16];
#pragma unroll
    for (int m = 0; m < 16; ++m) acc[m] = 0.f;
    const float* yrow = y2 + t*32768 + c;
    const float4* c0t4 = reinterpret_cast<const float4*>(c0t) + o0h*4;
#pragma unroll 4
    for (int k = 0; k < 128; ++k) {
        float v = yrow[k*256];                        // coalesced 1KB/wave-pair
#pragma unroll
        for (int m = 0; m < 4; ++m) {
            float4 cv = c0t4[k*8 + m];                // wave-uniform
            acc[4*m+0] += cv.x * v;
            acc[4*m+1] += cv.y * v;
            acc[4*m+2] += cv.z * v;
            acc[4*m+3] += cv.w * v;
        }
    }
#pragma unroll
    for (int m = 0; m < 16; ++m) {
        int o0 = o0h*16 + m;
        out[t*8192 + o0*256 + c] = acc[m] + bias[o0*256 + c];
    }
}

extern "C" void kernel_launch(void* const* d_in, const int* in_sizes, int n_in,
                              void* d_out, int out_size, void* d_ws, size_t ws_size,
                              hipStream_t stream) {
    const float* x    = (const float*)d_in[0];
    const float* c0   = (const float*)d_in[1];
    const float* c1   = (const float*)d_in[2];
    const float* c2   = (const float*)d_in[3];
    const float* bias = (const float*)d_in[4];
    float* out = (float*)d_out;

    float* y1  = (float*)d_ws;          // 4,194,304 floats (16 MB)
    float* y2  = y1 + 4194304;          // 4,194,304 floats (16 MB)
    float* c0t = y2 + 4194304;          // 4,096 floats

    tt_k1<<<4096, 256, 0, stream>>>(x, c2, y1);
    tt_k2<<<512, 128, 0, stream>>>(y1, c1, c0, y2, c0t);
    tt_k3<<<256, 256, 0, stream>>>(y2, c0t, bias, out);
}

// Round 2
// 96.248 us; speedup vs baseline: 1.6035x; 1.6035x over previous
//
#include <hip/hip_runtime.h>

// TT-linear fp32, factored:
//   y1[t,i0,o2,i1,r2] = sum_i2 x[t,i0,i1,i2] * c2[r2,o2,i2]       (LDS only)
//   y2[t,k=i0*4+r1, c=o1*16+o2] = sum_{i1r2} y1 * c1[r1o1, i1r2]  (ws, [t][k][c])
//   out[t, o0*256+c] = sum_k y2[t,k,c] * c0t[k,o0] + bias
//
// K12: block = (t, i0 quad). 1024 blocks x 256 thr (4 waves). 4 blocks/CU.
//   lane <-> column (i0loc, o2); wave <-> r1 (readfirstlane => c1 is s_load).
__global__ __launch_bounds__(256, 4) void tt_k12(
    const float* __restrict__ x, const float* __restrict__ c1,
    const float* __restrict__ c2, const float* __restrict__ c0,
    float* __restrict__ y2, float* __restrict__ c0t)
{
    __shared__ float xs[64 * 20];    // [i0loc*16+i1][i2 pad 16->20]
    __shared__ float c2s[64 * 20];   // [r2*16+o2][i2 pad 16->20]
    __shared__ float y1s[64 * 68];   // [i0loc*16+o2][j=i1*4+r2 pad 64->68]
    const int tid = threadIdx.x;
    const int b = blockIdx.x;
    const int t = b >> 3, i0q = b & 7;

    // fold-in: first 16 blocks build c0t[k*32 + o0] = c0[o0*128 + k]
    if (b < 16) {
        int idx = (b << 8) | tid;                       // 4096 elems
        c0t[idx] = c0[(idx & 31) * 128 + (idx >> 5)];
    }

    // stage x tile (1024 floats) and c2 (4096 floats), coalesced float4
    {
        float4 v = reinterpret_cast<const float4*>(x + t * 8192 + i0q * 1024)[tid];
        *reinterpret_cast<float4*>(&xs[(tid >> 2) * 20 + ((tid & 3) << 2)]) = v;
    }
#pragma unroll
    for (int m = 0; m < 4; ++m) {
        int q = (m << 8) | tid;                         // 1024 quads
        float4 v = reinterpret_cast<const float4*>(c2)[q];
        *reinterpret_cast<float4*>(&c2s[(q >> 2) * 20 + ((q & 3) << 2)]) = v;
    }
    __syncthreads();

    // ---- K1 phase: thread = (i0loc, o2, i1q); computes 4 i1 x 4 r2 quads
    {
        const int i0loc = tid >> 6;
        const int o2 = (tid >> 2) & 15;
        const int i1q = tid & 3;
        float cw[4][16];
#pragma unroll
        for (int r2 = 0; r2 < 4; ++r2)
#pragma unroll
            for (int m = 0; m < 4; ++m) {
                float4 v = *reinterpret_cast<const float4*>(
                    &c2s[((r2 << 4) | o2) * 20 + (m << 2)]);
                cw[r2][4*m+0] = v.x; cw[r2][4*m+1] = v.y;
                cw[r2][4*m+2] = v.z; cw[r2][4*m+3] = v.w;
            }
#pragma unroll
        for (int d = 0; d < 4; ++d) {
            int i1 = (i1q << 2) | d;
            float xv[16];
#pragma unroll
            for (int m = 0; m < 4; ++m) {
                float4 v = *reinterpret_cast<const float4*>(
                    &xs[((i0loc << 4) | i1) * 20 + (m << 2)]);
                xv[4*m+0] = v.x; xv[4*m+1] = v.y; xv[4*m+2] = v.z; xv[4*m+3] = v.w;
            }
            float s[4];
#pragma unroll
            for (int r2 = 0; r2 < 4; ++r2) {
                float a = 0.f;
#pragma unroll
                for (int i2 = 0; i2 < 16; ++i2) a += xv[i2] * cw[r2][i2];
                s[r2] = a;
            }
            *reinterpret_cast<float4*>(&y1s[((i0loc << 4) | o2) * 68 + (i1 << 2)]) =
                make_float4(s[0], s[1], s[2], s[3]);
        }
    }
    __syncthreads();

    // ---- K2 phase: 64x64 matvec, acc over o1 (16), K = i1r2 (64)
    const int lane = tid & 63;
    const int w = __builtin_amdgcn_readfirstlane(tid >> 6);   // r1, wave-uniform
    float acc[16];
#pragma unroll
    for (int r = 0; r < 16; ++r) acc[r] = 0.f;
    const float* yrow = &y1s[lane * 68];
    const float4* c14 = reinterpret_cast<const float4*>(c1);
#pragma unroll 2
    for (int jq = 0; jq < 16; ++jq) {
        float4 yv = *reinterpret_cast<const float4*>(yrow + (jq << 2));
#pragma unroll
        for (int o1 = 0; o1 < 16; ++o1) {
            float4 cv = c14[(((w << 4) | o1) << 4) | jq];     // wave-uniform -> SMEM
            acc[o1] += yv.x*cv.x + yv.y*cv.y + yv.z*cv.z + yv.w*cv.w;
        }
    }
    const int k = (((i0q << 2) | (lane >> 4)) << 2) | w;      // i0*4 + r1
    float* outp = y2 + (((t << 7) | k) << 8) + (lane & 15);   // [t][k][c], c=o1*16+o2
#pragma unroll
    for (int o1 = 0; o1 < 16; ++o1) outp[o1 << 4] = acc[o1];
}

// K3: block = (t, c-quarter). 512 blocks x 256 thr. wave <-> k-quarter.
// lane <-> c (64 cols); acc[32] over o0; c0t via uniform s_load.
__global__ __launch_bounds__(256, 2) void tt_k3(
    const float* __restrict__ y2, const float* __restrict__ c0t,
    const float* __restrict__ bias, float* __restrict__ out)
{
    __shared__ float po[3][32][64];
    const int tid = threadIdx.x;
    const int lane = tid & 63;
    const int kh = __builtin_amdgcn_readfirstlane(tid >> 6);
    const int b = blockIdx.x;
    const int t = b >> 2;
    const int c = ((b & 3) << 6) | lane;
    float acc[32];
#pragma unroll
    for (int m = 0; m < 32; ++m) acc[m] = 0.f;
    const float* yp = y2 + (t << 15) + c;
    const float4* c04 = reinterpret_cast<const float4*>(c0t);
#pragma unroll 4
    for (int kk = 0; kk < 32; ++kk) {
        int k = (kh << 5) | kk;
        float v = yp[k << 8];                              // coalesced 256B/wave
#pragma unroll
        for (int m = 0; m < 8; ++m) {
            float4 cv = c04[(k << 3) | m];                 // wave-uniform -> SMEM
            acc[4*m+0] += cv.x * v;
            acc[4*m+1] += cv.y * v;
            acc[4*m+2] += cv.z * v;
            acc[4*m+3] += cv.w * v;
        }
    }
    if (kh != 0) {
#pragma unroll
        for (int m = 0; m < 32; ++m) po[kh-1][m][lane] = acc[m];
    }
    __syncthreads();
    if (kh == 0) {
#pragma unroll
        for (int m = 0; m < 32; ++m) {
            float s = acc[m] + po[0][m][lane] + po[1][m][lane] + po[2][m][lane]
                    + bias[(m << 8) | c];
            out[(t << 13) | (m << 8) | c] = s;
        }
    }
}

extern "C" void kernel_launch(void* const* d_in, const int* in_sizes, int n_in,
                              void* d_out, int out_size, void* d_ws, size_t ws_size,
                              hipStream_t stream) {
    const float* x    = (const float*)d_in[0];
    const float* c0   = (const float*)d_in[1];
    const float* c1   = (const float*)d_in[2];
    const float* c2   = (const float*)d_in[3];
    const float* bias = (const float*)d_in[4];
    float* out = (float*)d_out;

    float* y2  = (float*)d_ws;             // 128*128*256 = 4,194,304 floats (16.8 MB)
    float* c0t = y2 + 4194304;             // 4,096 floats

    tt_k12<<<1024, 256, 0, stream>>>(x, c1, c2, c0, y2, c0t);
    tt_k3 <<< 512, 256, 0, stream>>>(y2, c0t, bias, out);
}